// Round 17
// baseline (2464.309 us; speedup 1.0000x reference)
//
#include <hip/hip_runtime.h>
#include <hip/hip_bf16.h>
#include <math.h>

#define T_DIM 128
#define B_DIM 256
#define H_DIM 1024
#define N3    3072
#define KC    3072   // combined K for gates GEMM: 2048 (e) + 1024 (h)
#define KTC   96     // KC/32
#define KTP   32     // H_DIM/32

typedef __attribute__((ext_vector_type(8))) short short8;
typedef __attribute__((ext_vector_type(4))) float float4v;
typedef __attribute__((ext_vector_type(4))) unsigned short ushort4v;

__device__ __forceinline__ unsigned short f2bf(float f) {
  union { float f; unsigned u; } v; v.f = f;
  unsigned u = v.u;
  unsigned r = u + 0x7FFFu + ((u >> 16) & 1u);
  return (unsigned short)(r >> 16);
}

// A-fragment offset for MFMA 16x16x32: lane l holds A[m=16mt+(l&15)][k=32kt+(l>>4)*8+i]
// stored at ((mt*KT + kt)*64 + l)*8 + i
__device__ __forceinline__ size_t afrag(int m, int k, int KT) {
  return ((((size_t)(m >> 4) * KT) + (k >> 5)) * 64
          + ((((k >> 3) & 3) << 4) | (m & 15))) * 8 + (k & 7);
}

__device__ __forceinline__ void store_bf4(unsigned short* p, const float* v) {
  ushort4v u;
  u.x = f2bf(v[0]); u.y = f2bf(v[1]); u.z = f2bf(v[2]); u.w = f2bf(v[3]);
  *(ushort4v*)p = u;
}

__device__ __forceinline__ float sigm(float x) { return 1.f / (1.f + __expf(-x)); }

// async global->LDS, 16 B/lane. gsrc is per-lane; ldst must be wave-uniform
// (HW writes lane data at ldst + lane*16).
__device__ __forceinline__ void glds16(const void* gsrc, void* ldst) {
  __builtin_amdgcn_global_load_lds(
      (const __attribute__((address_space(1))) unsigned int*)gsrc,
      (__attribute__((address_space(3))) unsigned int*)ldst, 16, 0, 0);
}

// ---------------- resets dtype detection + decode ----------------
__global__ void detect_resets(const int* __restrict__ r, int* __restrict__ flag) {
  __shared__ int f;
  if (threadIdx.x == 0) f = 0;
  __syncthreads();
  int loc = 0;
  for (int i = threadIdx.x; i < 8192; i += 256) {
    if ((unsigned)r[i] > 1u) loc = 1;
  }
  if (loc) f = 1;
  __syncthreads();
  if (threadIdx.x == 0) *flag = f;
}

__global__ __launch_bounds__(256) void decode_resets(
    const void* __restrict__ resets, const int* __restrict__ rflag,
    unsigned char* __restrict__ rb) {
  int t = blockIdx.x, b = threadIdx.x;
  int v;
  if (*rflag) v = (int)((const unsigned char*)resets)[t * B_DIM + b];
  else        v = ((const int*)resets)[t * B_DIM + b];
  rb[t * B_DIM + b] = (v != 0) ? 1 : 0;
}

// ---------------- weight conversion ----------------
// Gates weights, virtual N = 64 jt * 4 groups * 16 cols. group g:
//   0 = r, 1 = z (Wi rows k<2048 | Wh rows k>=2048), 2 = n_i (k<2048), 3 = n_h (k>=2048)
__global__ __launch_bounds__(256) void convert_gates(
    const float* __restrict__ Wi, const float* __restrict__ Wh,
    unsigned short* __restrict__ Wg) {
  int nt = blockIdx.x;   // 0..255
  int kt = blockIdx.y;   // 0..95
  int jt = nt >> 2, g = nt & 3;
  size_t base = ((size_t)nt * KTC + kt) * 512;
  for (int e = threadIdx.x; e < 512; e += 256) {
    int i = e & 7, l = (e >> 3) & 63;
    int k = (kt << 5) + ((l >> 4) << 3) + i;
    int j = (jt << 4) + (l & 15);
    float v = 0.f;
    if (g == 0) v = (k < 2048) ? Wi[(size_t)k * N3 + j] : Wh[(size_t)(k - 2048) * N3 + j];
    else if (g == 1) v = (k < 2048) ? Wi[(size_t)k * N3 + 1024 + j] : Wh[(size_t)(k - 2048) * N3 + 1024 + j];
    else if (g == 2) { if (k < 2048) v = Wi[(size_t)k * N3 + 2048 + j]; }
    else             { if (k >= 2048) v = Wh[(size_t)(k - 2048) * N3 + 2048 + j]; }
    Wg[base + e] = f2bf(v);
  }
}

__global__ __launch_bounds__(256) void convert_wp(const float* __restrict__ W,
                                                  unsigned short* __restrict__ Wsw) {
  int nt = blockIdx.x;   // 0..63
  int kt = blockIdx.y;   // 0..31
  size_t base = ((size_t)nt * KTP + kt) * 512;
  for (int e = threadIdx.x; e < 512; e += 256) {
    int i = e & 7, l = (e >> 3) & 63;
    int k = (kt << 5) + ((l >> 4) << 3) + i;
    int n = (nt << 4) + (l & 15);
    Wsw[base + e] = f2bf(W[(size_t)k * H_DIM + n]);
  }
}

// ---------------- init (t = 0 state) ----------------
__global__ __launch_bounds__(256) void init_state(
    const float* __restrict__ a_all,
    unsigned short* __restrict__ A0, float* __restrict__ h0,
    float* __restrict__ err_out) {
  int b = blockIdx.x, tid = threadIdx.x;
  int j0 = tid * 4;
  const float* arow = a_all + (size_t)b * H_DIM;
  float pv[4], nv[4], zz[4] = {0.f, 0.f, 0.f, 0.f};
  float s = 0.f;
#pragma unroll
  for (int jj = 0; jj < 4; ++jj) {
    float a = arow[j0 + jj];
    pv[jj] = fmaxf(a, 0.f);
    nv[jj] = fmaxf(-a, 0.f);
    s += pv[jj] + nv[jj];
    h0[(size_t)b * H_DIM + j0 + jj] = 0.f;
  }
  store_bf4(A0 + afrag(b, j0, KTC), pv);
  store_bf4(A0 + afrag(b, 1024 + j0, KTC), nv);
  store_bf4(A0 + afrag(b, 2048 + j0, KTC), zz);
  __shared__ float red[256];
  red[tid] = s;
  __syncthreads();
  for (int st = 128; st > 0; st >>= 1) {
    if (tid < st) red[tid] += red[tid + st];
    __syncthreads();
  }
  if (tid == 0) err_out[b] = red[0] * (1.0f / (float)H_DIM);
}

// ---------------- fused gates GEMM + GRU update (split-depth glds pipeline) ----------------
// grid 256 (1 block/CU), 512 threads = 8 waves. Block b: jt = b & 63 (XCD-pinned
// weight slice), rg2 = b >> 6 (64 rows = 4 m-tiles). Wave w owns kt = 8c + w,
// c = 0..11. Split pipelines: A-fragments (IC-latency ~900cy) prefetched at
// DISTANCE 2 (triple-buffered, 96 KB); W-fragments (L2 ~200cy) at distance 1
// (double-buffered, 48 KB). Issue order fixed: prologue {A0,A1,W0}=11 ops;
// iter c issues A(c+2) [c<=9] then W(c+1) [c<=10]. Static waits: need-through
// = W(c) @ pos 7c+11, issued = 7c+18 -> vmcnt(7) for c<=9; vmcnt(3) @ c=10;
// vmcnt(0) @ c=11. No barriers in the k-loop (wave-private LDS).
__global__ __launch_bounds__(512, 1) void gates_fused(
    const unsigned short* __restrict__ A_sw, const unsigned short* __restrict__ Wg,
    const float* __restrict__ b_i, const float* __restrict__ b_hn,
    const float* __restrict__ h_in, float* __restrict__ h_out,
    unsigned short* __restrict__ A_next,
    const unsigned char* __restrict__ rb,
    float* __restrict__ r_out, int t) {
  int lane = threadIdx.x & 63, wave = threadIdx.x >> 6;
  int b = blockIdx.x;
  int jt = b & 63;
  int rg2 = b >> 6;   // 0..3

  __shared__ short8 stA[3][8][4][64];   // 96 KB: [buf][wave][frag][lane]
  __shared__ short8 stW[2][8][3][64];   // 48 KB

  const short8* A8 = (const short8*)A_sw;
  const short8* B8 = (const short8*)Wg;

  const short8* aB0 = A8 + ((size_t)(rg2 * 4 + 0) * KTC) * 64;
  const short8* aB1 = A8 + ((size_t)(rg2 * 4 + 1) * KTC) * 64;
  const short8* aB2 = A8 + ((size_t)(rg2 * 4 + 2) * KTC) * 64;
  const short8* aB3 = A8 + ((size_t)(rg2 * 4 + 3) * KTC) * 64;
  const short8* wBr = B8 + ((size_t)(jt * 4 + 0) * KTC) * 64;
  const short8* wBz = B8 + ((size_t)(jt * 4 + 1) * KTC) * 64;
  const short8* wBi = B8 + ((size_t)(jt * 4 + 2) * KTC) * 64;
  const short8* wBh = B8 + ((size_t)(jt * 4 + 3) * KTC) * 64;

  float4v acc[4][4];
#pragma unroll
  for (int mi = 0; mi < 4; ++mi)
#pragma unroll
    for (int g = 0; g < 4; ++g) acc[mi][g] = (float4v){0.f, 0.f, 0.f, 0.f};

#define STAGE_A(cc)                                                            \
  {                                                                            \
    size_t o_ = (size_t)(8 * (cc) + wave) * 64 + lane;                         \
    short8* d_ = &stA[(cc) % 3][wave][0][0];                                   \
    glds16((const void*)(aB0 + o_), (void*)(d_ + 0 * 64));                     \
    glds16((const void*)(aB1 + o_), (void*)(d_ + 1 * 64));                     \
    glds16((const void*)(aB2 + o_), (void*)(d_ + 2 * 64));                     \
    glds16((const void*)(aB3 + o_), (void*)(d_ + 3 * 64));                     \
  }
#define STAGE_W(cc, NSRC)                                                      \
  {                                                                            \
    size_t o_ = (size_t)(8 * (cc) + wave) * 64 + lane;                         \
    short8* d_ = &stW[(cc) & 1][wave][0][0];                                   \
    glds16((const void*)(wBr + o_), (void*)(d_ + 0 * 64));                     \
    glds16((const void*)(wBz + o_), (void*)(d_ + 1 * 64));                     \
    glds16((const void*)(NSRC + o_), (void*)(d_ + 2 * 64));                    \
  }

  // prologue: A(0), A(1), W(0)  (11 ops in flight)
  STAGE_A(0)
  STAGE_A(1)
  STAGE_W(0, wBi)

#pragma unroll
  for (int c = 0; c < 12; ++c) {
    if (c <= 9) STAGE_A(c + 2)
    if (c <= 10) {
      if (c + 1 < 8) STAGE_W(c + 1, wBi)
      else           STAGE_W(c + 1, wBh)
    }
    if (c <= 9)      asm volatile("s_waitcnt vmcnt(7)" ::: "memory");
    else if (c == 10) asm volatile("s_waitcnt vmcnt(3)" ::: "memory");
    else              asm volatile("s_waitcnt vmcnt(0)" ::: "memory");
    __builtin_amdgcn_sched_barrier(0);

    const short8* fa = &stA[c % 3][wave][0][0];
    const short8* fw = &stW[c & 1][wave][0][0];
    short8 A0f = fa[0 * 64 + lane];
    short8 A1f = fa[1 * 64 + lane];
    short8 A2f = fa[2 * 64 + lane];
    short8 A3f = fa[3 * 64 + lane];
    short8 Rf  = fw[0 * 64 + lane];
    short8 Zf  = fw[1 * 64 + lane];
    short8 Nf  = fw[2 * 64 + lane];

    const int GS = (c < 8) ? 2 : 3;   // static after unroll
    acc[0][0]  = __builtin_amdgcn_mfma_f32_16x16x32_bf16(A0f, Rf, acc[0][0], 0, 0, 0);
    acc[1][0]  = __builtin_amdgcn_mfma_f32_16x16x32_bf16(A1f, Rf, acc[1][0], 0, 0, 0);
    acc[2][0]  = __builtin_amdgcn_mfma_f32_16x16x32_bf16(A2f, Rf, acc[2][0], 0, 0, 0);
    acc[3][0]  = __builtin_amdgcn_mfma_f32_16x16x32_bf16(A3f, Rf, acc[3][0], 0, 0, 0);
    acc[0][1]  = __builtin_amdgcn_mfma_f32_16x16x32_bf16(A0f, Zf, acc[0][1], 0, 0, 0);
    acc[1][1]  = __builtin_amdgcn_mfma_f32_16x16x32_bf16(A1f, Zf, acc[1][1], 0, 0, 0);
    acc[2][1]  = __builtin_amdgcn_mfma_f32_16x16x32_bf16(A2f, Zf, acc[2][1], 0, 0, 0);
    acc[3][1]  = __builtin_amdgcn_mfma_f32_16x16x32_bf16(A3f, Zf, acc[3][1], 0, 0, 0);
    acc[0][GS] = __builtin_amdgcn_mfma_f32_16x16x32_bf16(A0f, Nf, acc[0][GS], 0, 0, 0);
    acc[1][GS] = __builtin_amdgcn_mfma_f32_16x16x32_bf16(A1f, Nf, acc[1][GS], 0, 0, 0);
    acc[2][GS] = __builtin_amdgcn_mfma_f32_16x16x32_bf16(A2f, Nf, acc[2][GS], 0, 0, 0);
    acc[3][GS] = __builtin_amdgcn_mfma_f32_16x16x32_bf16(A3f, Nf, acc[3][GS], 0, 0, 0);
  }
#undef STAGE_A
#undef STAGE_W

  __syncthreads();   // all waves done with stage LDS; overlay reduce buffer

  // two-stage reduce (r12-identical), red overlays stA: [4][4][2][64] float4v
  float4v (*red)[4][2][64] = (float4v (*)[4][2][64])(&stA[0][0][0][0]);

#pragma unroll
  for (int hh = 0; hh < 2; ++hh) {
    if (wave >= 4) {
#pragma unroll
      for (int mi = 0; mi < 4; ++mi) {
        red[wave - 4][mi][0][lane] = acc[mi][2 * hh];
        red[wave - 4][mi][1][lane] = acc[mi][2 * hh + 1];
      }
    }
    __syncthreads();
    if (wave < 4) {
#pragma unroll
      for (int mi = 0; mi < 4; ++mi) {
        acc[mi][2 * hh]     += red[wave][mi][0][lane];
        acc[mi][2 * hh + 1] += red[wave][mi][1][lane];
      }
    }
    __syncthreads();
  }
  float4v accs[4];
#pragma unroll
  for (int hh = 0; hh < 2; ++hh) {
    if (wave < 4) {
#pragma unroll
      for (int mi = 0; mi < 4; ++mi) {
        red[wave][mi][0][lane] = acc[mi][2 * hh];
        red[wave][mi][1][lane] = acc[mi][2 * hh + 1];
      }
    }
    __syncthreads();
    if (wave < 4) {
      float4v s0 = red[0][wave][0][lane];
      float4v s1 = red[0][wave][1][lane];
#pragma unroll
      for (int w = 1; w < 4; ++w) {
        s0 += red[w][wave][0][lane];
        s1 += red[w][wave][1][lane];
      }
      accs[2 * hh] = s0; accs[2 * hh + 1] = s1;
    }
    __syncthreads();
  }

  // GRU epilogue (waves 0-3, 16 rows x 16 cols each)
  if (wave < 4) {
    int cl = lane & 15, q = lane >> 4;
    int jcol = (jt << 4) + cl;
    float br_ = b_i[jcol], bz_ = b_i[1024 + jcol], bn_ = b_i[2048 + jcol];
    float bh = b_hn[jcol];
    int row_base = rg2 * 64 + wave * 16 + q * 4;
#pragma unroll
    for (int rr = 0; rr < 4; ++rr) {
      int row = row_base + rr;
      float r = sigm(accs[0][rr] + br_);
      float z = sigm(accs[1][rr] + bz_);
      float n = tanhf(accs[2][rr] + bn_ + r * (accs[3][rr] + bh));
      float hv = h_in[(size_t)row * H_DIM + jcol];
      float nh = (1.f - z) * n + z * hv;
      r_out[((size_t)t * B_DIM + row) * H_DIM + jcol] = nh;
      if (t < T_DIM - 1) {
        int rst = rb[(t + 1) * B_DIM + row];
        float hm = rst ? 0.f : nh;
        h_out[(size_t)row * H_DIM + jcol] = hm;
        A_next[afrag(row, 2048 + jcol, KTC)] = f2bf(hm);  // pred + next gates read this
      }
    }
  }
}

// ---------------- fused pred GEMM + e_t / err for step t+1 (r12-identical) ----------------
__global__ __launch_bounds__(512, 2) void pred_fused(
    const unsigned short* __restrict__ A_next, const unsigned short* __restrict__ Wp,
    const float* __restrict__ b_p, const float* __restrict__ a_all,
    const unsigned char* __restrict__ rb,
    unsigned short* __restrict__ A_next_w, float* __restrict__ err_out, int t) {
  int lane = threadIdx.x & 63, wave = threadIdx.x >> 6;
  int b = blockIdx.x;
  int ntq = b & 15, mt = b >> 4;

  const short8* A8 = (const short8*)A_next;
  const short8* B8 = (const short8*)Wp;

  const short8* hap = A8 + ((size_t)mt * KTC + 64) * 64 + lane;
  const short8* bp0 = B8 + ((size_t)(ntq * 4 + 0) * KTP) * 64 + lane;
  const short8* bp1 = B8 + ((size_t)(ntq * 4 + 1) * KTP) * 64 + lane;
  const short8* bp2 = B8 + ((size_t)(ntq * 4 + 2) * KTP) * 64 + lane;
  const short8* bp3 = B8 + ((size_t)(ntq * 4 + 3) * KTP) * 64 + lane;

  float4v acc[4];
#pragma unroll
  for (int n = 0; n < 4; ++n) acc[n] = (float4v){0.f, 0.f, 0.f, 0.f};

  {
    int pk0 = wave * 4;   // 8 waves x 4 kt = 32 kt
    short8 Aa[4], B0a[4], B1a[4], B2a[4], B3a[4];
#pragma unroll
    for (int kk = 0; kk < 4; ++kk) Aa[kk] = hap[(size_t)(pk0 + kk) * 64];
#pragma unroll
    for (int kk = 0; kk < 4; ++kk) {
      size_t o = (size_t)(pk0 + kk) * 64;
      B0a[kk] = bp0[o]; B1a[kk] = bp1[o]; B2a[kk] = bp2[o]; B3a[kk] = bp3[o];
    }
#pragma unroll
    for (int kk = 0; kk < 4; ++kk) {
      acc[0] = __builtin_amdgcn_mfma_f32_16x16x32_bf16(Aa[kk], B0a[kk], acc[0], 0, 0, 0);
      acc[1] = __builtin_amdgcn_mfma_f32_16x16x32_bf16(Aa[kk], B1a[kk], acc[1], 0, 0, 0);
      acc[2] = __builtin_amdgcn_mfma_f32_16x16x32_bf16(Aa[kk], B2a[kk], acc[2], 0, 0, 0);
      acc[3] = __builtin_amdgcn_mfma_f32_16x16x32_bf16(Aa[kk], B3a[kk], acc[3], 0, 0, 0);
    }
  }

  __shared__ float4v red[8][4][64];        // 32 KB
  __shared__ float rsum_red[4][4][4];
#pragma unroll
  for (int n = 0; n < 4; ++n) red[wave][n][lane] = acc[n];
  __syncthreads();

  int cl = lane & 15, q = lane >> 4;

  if (wave < 4) {
    float4v s = red[0][wave][lane];
#pragma unroll
    for (int w = 1; w < 8; ++w) s += red[w][wave][lane];

    int coln = (ntq * 4 + wave) * 16 + cl;
    float bp = b_p[coln];
    float rsum[4];
#pragma unroll
    for (int rr = 0; rr < 4; ++rr) {
      int row = mt * 16 + q * 4 + rr;
      float ah = fmaxf(s[rr] + bp, 0.f);
      int rst = rb[(t + 1) * B_DIM + row];
      float am = rst ? 0.f : ah;
      float av = a_all[((size_t)(t + 1) * B_DIM + row) * H_DIM + coln];
      float d = av - am;
      float pos = fmaxf(d, 0.f), neg = fmaxf(-d, 0.f);
      A_next_w[afrag(row, coln, KTC)] = f2bf(pos);
      A_next_w[afrag(row, 1024 + coln, KTC)] = f2bf(neg);
      rsum[rr] = pos + neg;
    }
#pragma unroll
    for (int rr = 0; rr < 4; ++rr) {
      float sv = rsum[rr];
      sv += __shfl_xor(sv, 1);
      sv += __shfl_xor(sv, 2);
      sv += __shfl_xor(sv, 4);
      sv += __shfl_xor(sv, 8);
      if (cl == 0) rsum_red[wave][q][rr] = sv;
    }
  }
  __syncthreads();
  if (wave == 0 && lane < 16) {
    int qq = lane >> 2, rr = lane & 3;
    float sv = rsum_red[0][qq][rr] + rsum_red[1][qq][rr]
             + rsum_red[2][qq][rr] + rsum_red[3][qq][rr];
    int row = mt * 16 + qq * 4 + rr;
    atomicAdd(err_out + (size_t)(t + 1) * B_DIM + row, sv * (1.0f / (float)H_DIM));
  }
}

// ---------------- launch ----------------
extern "C" void kernel_launch(void* const* d_in, const int* in_sizes, int n_in,
                              void* d_out, int out_size, void* d_ws, size_t ws_size,
                              hipStream_t stream) {
  (void)in_sizes; (void)n_in; (void)out_size; (void)ws_size;
  const float* a_all = (const float*)d_in[0];
  const void*  resets = d_in[1];
  const float* W_i  = (const float*)d_in[2];
  const float* b_i  = (const float*)d_in[3];
  const float* W_h  = (const float*)d_in[4];
  const float* b_hn = (const float*)d_in[5];
  const float* W_p  = (const float*)d_in[6];
  const float* b_p  = (const float*)d_in[7];

  float* r_out = (float*)d_out;
  float* err_out = r_out + (size_t)T_DIM * B_DIM * H_DIM;

  char* ws = (char*)d_ws;
  unsigned short* Wg_sw = (unsigned short*)ws; ws += (size_t)256 * 16 * KC * 2;     // 25.2 MB
  unsigned short* Wp_sw = (unsigned short*)ws; ws += (size_t)H_DIM * H_DIM * 2;     // 2 MB
  unsigned short* A0    = (unsigned short*)ws; ws += (size_t)B_DIM * KC * 2;        // 1.5 MB
  unsigned short* A1    = (unsigned short*)ws; ws += (size_t)B_DIM * KC * 2;        // 1.5 MB
  float* h0 = (float*)ws; ws += (size_t)B_DIM * H_DIM * 4;                          // 1 MB
  float* h1 = (float*)ws; ws += (size_t)B_DIM * H_DIM * 4;                          // 1 MB
  unsigned char* rb = (unsigned char*)ws; ws += T_DIM * B_DIM;                      // 32 KB
  int* rflag = (int*)ws; ws += 256;

  hipMemsetAsync(err_out, 0, (size_t)T_DIM * B_DIM * sizeof(float), stream);
  detect_resets<<<1, 256, 0, stream>>>((const int*)resets, rflag);
  decode_resets<<<T_DIM, 256, 0, stream>>>(resets, rflag, rb);
  convert_gates<<<dim3(256, KTC), 256, 0, stream>>>(W_i, W_h, Wg_sw);
  convert_wp<<<dim3(H_DIM / 16, KTP), 256, 0, stream>>>(W_p, Wp_sw);
  init_state<<<B_DIM, 256, 0, stream>>>(a_all, A0, h0, err_out);

  for (int t = 0; t < T_DIM; ++t) {
    const unsigned short* Acur = (t & 1) ? A1 : A0;
    unsigned short* Anext      = (t & 1) ? A0 : A1;
    const float* hcur = (t & 1) ? h1 : h0;
    float* hnext      = (t & 1) ? h0 : h1;
    gates_fused<<<256, 512, 0, stream>>>(
        Acur, Wg_sw, b_i, b_hn, hcur, hnext, Anext, rb, r_out, t);
    if (t < T_DIM - 1)
      pred_fused<<<256, 512, 0, stream>>>(
          Anext, Wp_sw, b_p, a_all, rb, Anext, err_out, t);
  }
}

// Round 18
// 2450.313 us; speedup vs baseline: 1.0057x; 1.0057x over previous
//
#include <hip/hip_runtime.h>
#include <hip/hip_bf16.h>
#include <math.h>

#define T_DIM 128
#define B_DIM 256
#define H_DIM 1024
#define N3    3072
#define KC    3072   // combined K for gates GEMM: 2048 (e) + 1024 (h)
#define KTC   96     // KC/32
#define KTP   32     // H_DIM/32

typedef __attribute__((ext_vector_type(8))) short short8;
typedef __attribute__((ext_vector_type(4))) float float4v;
typedef __attribute__((ext_vector_type(4))) unsigned short ushort4v;

__device__ __forceinline__ unsigned short f2bf(float f) {
  union { float f; unsigned u; } v; v.f = f;
  unsigned u = v.u;
  unsigned r = u + 0x7FFFu + ((u >> 16) & 1u);
  return (unsigned short)(r >> 16);
}

// A-fragment offset for MFMA 16x16x32: lane l holds A[m=16mt+(l&15)][k=32kt+(l>>4)*8+i]
// stored at ((mt*KT + kt)*64 + l)*8 + i
__device__ __forceinline__ size_t afrag(int m, int k, int KT) {
  return ((((size_t)(m >> 4) * KT) + (k >> 5)) * 64
          + ((((k >> 3) & 3) << 4) | (m & 15))) * 8 + (k & 7);
}

__device__ __forceinline__ void store_bf4(unsigned short* p, const float* v) {
  ushort4v u;
  u.x = f2bf(v[0]); u.y = f2bf(v[1]); u.z = f2bf(v[2]); u.w = f2bf(v[3]);
  *(ushort4v*)p = u;
}

__device__ __forceinline__ float sigm(float x) { return 1.f / (1.f + __expf(-x)); }

// async global->LDS, 16 B/lane. gsrc is per-lane; ldst must be wave-uniform
// (HW writes lane data at ldst + lane*16).
__device__ __forceinline__ void glds16(const void* gsrc, void* ldst) {
  __builtin_amdgcn_global_load_lds(
      (const __attribute__((address_space(1))) unsigned int*)gsrc,
      (__attribute__((address_space(3))) unsigned int*)ldst, 16, 0, 0);
}

// ---------------- resets dtype detection + decode ----------------
__global__ void detect_resets(const int* __restrict__ r, int* __restrict__ flag) {
  __shared__ int f;
  if (threadIdx.x == 0) f = 0;
  __syncthreads();
  int loc = 0;
  for (int i = threadIdx.x; i < 8192; i += 256) {
    if ((unsigned)r[i] > 1u) loc = 1;
  }
  if (loc) f = 1;
  __syncthreads();
  if (threadIdx.x == 0) *flag = f;
}

__global__ __launch_bounds__(256) void decode_resets(
    const void* __restrict__ resets, const int* __restrict__ rflag,
    unsigned char* __restrict__ rb) {
  int t = blockIdx.x, b = threadIdx.x;
  int v;
  if (*rflag) v = (int)((const unsigned char*)resets)[t * B_DIM + b];
  else        v = ((const int*)resets)[t * B_DIM + b];
  rb[t * B_DIM + b] = (v != 0) ? 1 : 0;
}

// ---------------- weight conversion ----------------
// Gates weights, virtual N = 64 jt * 4 groups * 16 cols. group g:
//   0 = r, 1 = z (Wi rows k<2048 | Wh rows k>=2048), 2 = n_i (k<2048), 3 = n_h (k>=2048)
__global__ __launch_bounds__(256) void convert_gates(
    const float* __restrict__ Wi, const float* __restrict__ Wh,
    unsigned short* __restrict__ Wg) {
  int nt = blockIdx.x;   // 0..255
  int kt = blockIdx.y;   // 0..95
  int jt = nt >> 2, g = nt & 3;
  size_t base = ((size_t)nt * KTC + kt) * 512;
  for (int e = threadIdx.x; e < 512; e += 256) {
    int i = e & 7, l = (e >> 3) & 63;
    int k = (kt << 5) + ((l >> 4) << 3) + i;
    int j = (jt << 4) + (l & 15);
    float v = 0.f;
    if (g == 0) v = (k < 2048) ? Wi[(size_t)k * N3 + j] : Wh[(size_t)(k - 2048) * N3 + j];
    else if (g == 1) v = (k < 2048) ? Wi[(size_t)k * N3 + 1024 + j] : Wh[(size_t)(k - 2048) * N3 + 1024 + j];
    else if (g == 2) { if (k < 2048) v = Wi[(size_t)k * N3 + 2048 + j]; }
    else             { if (k >= 2048) v = Wh[(size_t)(k - 2048) * N3 + 2048 + j]; }
    Wg[base + e] = f2bf(v);
  }
}

__global__ __launch_bounds__(256) void convert_wp(const float* __restrict__ W,
                                                  unsigned short* __restrict__ Wsw) {
  int nt = blockIdx.x;   // 0..63
  int kt = blockIdx.y;   // 0..31
  size_t base = ((size_t)nt * KTP + kt) * 512;
  for (int e = threadIdx.x; e < 512; e += 256) {
    int i = e & 7, l = (e >> 3) & 63;
    int k = (kt << 5) + ((l >> 4) << 3) + i;
    int n = (nt << 4) + (l & 15);
    Wsw[base + e] = f2bf(W[(size_t)k * H_DIM + n]);
  }
}

// ---------------- init (t = 0 state) ----------------
__global__ __launch_bounds__(256) void init_state(
    const float* __restrict__ a_all,
    unsigned short* __restrict__ A0, float* __restrict__ h0,
    float* __restrict__ err_out) {
  int b = blockIdx.x, tid = threadIdx.x;
  int j0 = tid * 4;
  const float* arow = a_all + (size_t)b * H_DIM;
  float pv[4], nv[4], zz[4] = {0.f, 0.f, 0.f, 0.f};
  float s = 0.f;
#pragma unroll
  for (int jj = 0; jj < 4; ++jj) {
    float a = arow[j0 + jj];
    pv[jj] = fmaxf(a, 0.f);
    nv[jj] = fmaxf(-a, 0.f);
    s += pv[jj] + nv[jj];
    h0[(size_t)b * H_DIM + j0 + jj] = 0.f;
  }
  store_bf4(A0 + afrag(b, j0, KTC), pv);
  store_bf4(A0 + afrag(b, 1024 + j0, KTC), nv);
  store_bf4(A0 + afrag(b, 2048 + j0, KTC), zz);
  __shared__ float red[256];
  red[tid] = s;
  __syncthreads();
  for (int st = 128; st > 0; st >>= 1) {
    if (tid < st) red[tid] += red[tid + st];
    __syncthreads();
  }
  if (tid == 0) err_out[b] = red[0] * (1.0f / (float)H_DIM);
}

// ---------------- fused gates GEMM + GRU update (global_load_lds pipeline) ----------------
// grid 256 (1 block/CU), 512 threads = 8 waves. Block b: jt = b & 63 (XCD-pinned
// weight slice: XCD = b%8 = jt%8), rg2 = b >> 6 (64 rows = 4 m-tiles).
// Wave w owns kt = 8c + w, c = 0..11 (12 kt). Per chunk: 7 async
// global_load_lds (4 A + 3 W, 1 KB each) into the wave's PRIVATE double-buffered
// LDS slot; counted s_waitcnt vmcnt(7) (never 0 until drain); 7 ds_read_b128;
// 12 MFMA. No barriers in the k-loop (wave-private data). c<8 = e-part (n_i,
// GS=2), c>=8 = h-part (n_h, GS=3) — uniform per chunk for every wave.
// After the loop: __syncthreads, then the stage LDS is overlaid by the r12
// two-stage reduce + GRU epilogue (unchanged).
__global__ __launch_bounds__(512, 1) void gates_fused(
    const unsigned short* __restrict__ A_sw, const unsigned short* __restrict__ Wg,
    const float* __restrict__ b_i, const float* __restrict__ b_hn,
    const float* __restrict__ h_in, float* __restrict__ h_out,
    unsigned short* __restrict__ A_next,
    const unsigned char* __restrict__ rb,
    float* __restrict__ r_out, int t) {
  int lane = threadIdx.x & 63, wave = threadIdx.x >> 6;
  int b = blockIdx.x;
  int jt = b & 63;
  int rg2 = b >> 6;   // 0..3

  __shared__ short8 stage[2][8][7][64];   // 112 KB: [buf][wave][frag][lane]

  const short8* A8 = (const short8*)A_sw;
  const short8* B8 = (const short8*)Wg;

  // global fragment bases (short8 units, without lane)
  const short8* aB0 = A8 + ((size_t)(rg2 * 4 + 0) * KTC) * 64;
  const short8* aB1 = A8 + ((size_t)(rg2 * 4 + 1) * KTC) * 64;
  const short8* aB2 = A8 + ((size_t)(rg2 * 4 + 2) * KTC) * 64;
  const short8* aB3 = A8 + ((size_t)(rg2 * 4 + 3) * KTC) * 64;
  const short8* wBr = B8 + ((size_t)(jt * 4 + 0) * KTC) * 64;
  const short8* wBz = B8 + ((size_t)(jt * 4 + 1) * KTC) * 64;
  const short8* wBi = B8 + ((size_t)(jt * 4 + 2) * KTC) * 64;
  const short8* wBh = B8 + ((size_t)(jt * 4 + 3) * KTC) * 64;

  float4v acc[4][4];
#pragma unroll
  for (int mi = 0; mi < 4; ++mi)
#pragma unroll
    for (int g = 0; g < 4; ++g) acc[mi][g] = (float4v){0.f, 0.f, 0.f, 0.f};

  // stage chunk cc (kt = 8*cc + wave) into buffer cc&1. A first (IC latency).
#define STAGE_CHUNK(cc, NSRC)                                                  \
  {                                                                            \
    int kt_ = 8 * (cc) + wave;                                                 \
    size_t o_ = (size_t)kt_ * 64 + lane;                                       \
    short8* d_ = &stage[(cc) & 1][wave][0][0];                                 \
    glds16((const void*)(aB0 + o_), (void*)(d_ + 0 * 64));                     \
    glds16((const void*)(aB1 + o_), (void*)(d_ + 1 * 64));                     \
    glds16((const void*)(aB2 + o_), (void*)(d_ + 2 * 64));                     \
    glds16((const void*)(aB3 + o_), (void*)(d_ + 3 * 64));                     \
    glds16((const void*)(wBr + o_), (void*)(d_ + 4 * 64));                     \
    glds16((const void*)(wBz + o_), (void*)(d_ + 5 * 64));                     \
    glds16((const void*)(NSRC + o_), (void*)(d_ + 6 * 64));                    \
  }

  STAGE_CHUNK(0, wBi);   // prologue: chunk 0 in flight (7 loads)

#pragma unroll
  for (int c = 0; c < 12; ++c) {
    if (c < 11) {
      if (c + 1 < 8) STAGE_CHUNK(c + 1, wBi)
      else           STAGE_CHUNK(c + 1, wBh)
      asm volatile("s_waitcnt vmcnt(7)" ::: "memory");   // chunk c landed
    } else {
      asm volatile("s_waitcnt vmcnt(0)" ::: "memory");   // drain last chunk
    }
    __builtin_amdgcn_sched_barrier(0);

    const short8* f = &stage[c & 1][wave][0][0];
    short8 A0f = f[0 * 64 + lane];
    short8 A1f = f[1 * 64 + lane];
    short8 A2f = f[2 * 64 + lane];
    short8 A3f = f[3 * 64 + lane];
    short8 Rf  = f[4 * 64 + lane];
    short8 Zf  = f[5 * 64 + lane];
    short8 Nf  = f[6 * 64 + lane];

    const int GS = (c < 8) ? 2 : 3;   // static after unroll
    acc[0][0]  = __builtin_amdgcn_mfma_f32_16x16x32_bf16(A0f, Rf, acc[0][0], 0, 0, 0);
    acc[1][0]  = __builtin_amdgcn_mfma_f32_16x16x32_bf16(A1f, Rf, acc[1][0], 0, 0, 0);
    acc[2][0]  = __builtin_amdgcn_mfma_f32_16x16x32_bf16(A2f, Rf, acc[2][0], 0, 0, 0);
    acc[3][0]  = __builtin_amdgcn_mfma_f32_16x16x32_bf16(A3f, Rf, acc[3][0], 0, 0, 0);
    acc[0][1]  = __builtin_amdgcn_mfma_f32_16x16x32_bf16(A0f, Zf, acc[0][1], 0, 0, 0);
    acc[1][1]  = __builtin_amdgcn_mfma_f32_16x16x32_bf16(A1f, Zf, acc[1][1], 0, 0, 0);
    acc[2][1]  = __builtin_amdgcn_mfma_f32_16x16x32_bf16(A2f, Zf, acc[2][1], 0, 0, 0);
    acc[3][1]  = __builtin_amdgcn_mfma_f32_16x16x32_bf16(A3f, Zf, acc[3][1], 0, 0, 0);
    acc[0][GS] = __builtin_amdgcn_mfma_f32_16x16x32_bf16(A0f, Nf, acc[0][GS], 0, 0, 0);
    acc[1][GS] = __builtin_amdgcn_mfma_f32_16x16x32_bf16(A1f, Nf, acc[1][GS], 0, 0, 0);
    acc[2][GS] = __builtin_amdgcn_mfma_f32_16x16x32_bf16(A2f, Nf, acc[2][GS], 0, 0, 0);
    acc[3][GS] = __builtin_amdgcn_mfma_f32_16x16x32_bf16(A3f, Nf, acc[3][GS], 0, 0, 0);
  }
#undef STAGE_CHUNK

  __syncthreads();   // all waves done with stage LDS; overlay reduce buffer

  // two-stage reduce (r12-identical), red overlays stage: [4][4][2][64] float4v
  float4v (*red)[4][2][64] = (float4v (*)[4][2][64])(&stage[0][0][0][0]);

#pragma unroll
  for (int hh = 0; hh < 2; ++hh) {
    if (wave >= 4) {
#pragma unroll
      for (int mi = 0; mi < 4; ++mi) {
        red[wave - 4][mi][0][lane] = acc[mi][2 * hh];
        red[wave - 4][mi][1][lane] = acc[mi][2 * hh + 1];
      }
    }
    __syncthreads();
    if (wave < 4) {
#pragma unroll
      for (int mi = 0; mi < 4; ++mi) {
        acc[mi][2 * hh]     += red[wave][mi][0][lane];
        acc[mi][2 * hh + 1] += red[wave][mi][1][lane];
      }
    }
    __syncthreads();
  }
  float4v accs[4];
#pragma unroll
  for (int hh = 0; hh < 2; ++hh) {
    if (wave < 4) {
#pragma unroll
      for (int mi = 0; mi < 4; ++mi) {
        red[wave][mi][0][lane] = acc[mi][2 * hh];
        red[wave][mi][1][lane] = acc[mi][2 * hh + 1];
      }
    }
    __syncthreads();
    if (wave < 4) {
      float4v s0 = red[0][wave][0][lane];
      float4v s1 = red[0][wave][1][lane];
#pragma unroll
      for (int w = 1; w < 4; ++w) {
        s0 += red[w][wave][0][lane];
        s1 += red[w][wave][1][lane];
      }
      accs[2 * hh] = s0; accs[2 * hh + 1] = s1;
    }
    __syncthreads();
  }

  // GRU epilogue (waves 0-3, 16 rows x 16 cols each)
  if (wave < 4) {
    int cl = lane & 15, q = lane >> 4;
    int jcol = (jt << 4) + cl;
    float br_ = b_i[jcol], bz_ = b_i[1024 + jcol], bn_ = b_i[2048 + jcol];
    float bh = b_hn[jcol];
    int row_base = rg2 * 64 + wave * 16 + q * 4;
#pragma unroll
    for (int rr = 0; rr < 4; ++rr) {
      int row = row_base + rr;
      float r = sigm(accs[0][rr] + br_);
      float z = sigm(accs[1][rr] + bz_);
      float n = tanhf(accs[2][rr] + bn_ + r * (accs[3][rr] + bh));
      float hv = h_in[(size_t)row * H_DIM + jcol];
      float nh = (1.f - z) * n + z * hv;
      r_out[((size_t)t * B_DIM + row) * H_DIM + jcol] = nh;
      if (t < T_DIM - 1) {
        int rst = rb[(t + 1) * B_DIM + row];
        float hm = rst ? 0.f : nh;
        h_out[(size_t)row * H_DIM + jcol] = hm;
        A_next[afrag(row, 2048 + jcol, KTC)] = f2bf(hm);  // pred + next gates read this
      }
    }
  }
}

// ---------------- fused pred GEMM + e_t / err for step t+1 (r12-identical) ----------------
__global__ __launch_bounds__(512, 2) void pred_fused(
    const unsigned short* __restrict__ A_next, const unsigned short* __restrict__ Wp,
    const float* __restrict__ b_p, const float* __restrict__ a_all,
    const unsigned char* __restrict__ rb,
    unsigned short* __restrict__ A_next_w, float* __restrict__ err_out, int t) {
  int lane = threadIdx.x & 63, wave = threadIdx.x >> 6;
  int b = blockIdx.x;
  int ntq = b & 15, mt = b >> 4;

  const short8* A8 = (const short8*)A_next;
  const short8* B8 = (const short8*)Wp;

  const short8* hap = A8 + ((size_t)mt * KTC + 64) * 64 + lane;
  const short8* bp0 = B8 + ((size_t)(ntq * 4 + 0) * KTP) * 64 + lane;
  const short8* bp1 = B8 + ((size_t)(ntq * 4 + 1) * KTP) * 64 + lane;
  const short8* bp2 = B8 + ((size_t)(ntq * 4 + 2) * KTP) * 64 + lane;
  const short8* bp3 = B8 + ((size_t)(ntq * 4 + 3) * KTP) * 64 + lane;

  float4v acc[4];
#pragma unroll
  for (int n = 0; n < 4; ++n) acc[n] = (float4v){0.f, 0.f, 0.f, 0.f};

  {
    int pk0 = wave * 4;   // 8 waves x 4 kt = 32 kt
    short8 Aa[4], B0a[4], B1a[4], B2a[4], B3a[4];
#pragma unroll
    for (int kk = 0; kk < 4; ++kk) Aa[kk] = hap[(size_t)(pk0 + kk) * 64];
#pragma unroll
    for (int kk = 0; kk < 4; ++kk) {
      size_t o = (size_t)(pk0 + kk) * 64;
      B0a[kk] = bp0[o]; B1a[kk] = bp1[o]; B2a[kk] = bp2[o]; B3a[kk] = bp3[o];
    }
#pragma unroll
    for (int kk = 0; kk < 4; ++kk) {
      acc[0] = __builtin_amdgcn_mfma_f32_16x16x32_bf16(Aa[kk], B0a[kk], acc[0], 0, 0, 0);
      acc[1] = __builtin_amdgcn_mfma_f32_16x16x32_bf16(Aa[kk], B1a[kk], acc[1], 0, 0, 0);
      acc[2] = __builtin_amdgcn_mfma_f32_16x16x32_bf16(Aa[kk], B2a[kk], acc[2], 0, 0, 0);
      acc[3] = __builtin_amdgcn_mfma_f32_16x16x32_bf16(Aa[kk], B3a[kk], acc[3], 0, 0, 0);
    }
  }

  __shared__ float4v red[8][4][64];        // 32 KB
  __shared__ float rsum_red[4][4][4];
#pragma unroll
  for (int n = 0; n < 4; ++n) red[wave][n][lane] = acc[n];
  __syncthreads();

  int cl = lane & 15, q = lane >> 4;

  if (wave < 4) {
    float4v s = red[0][wave][lane];
#pragma unroll
    for (int w = 1; w < 8; ++w) s += red[w][wave][lane];

    int coln = (ntq * 4 + wave) * 16 + cl;
    float bp = b_p[coln];
    float rsum[4];
#pragma unroll
    for (int rr = 0; rr < 4; ++rr) {
      int row = mt * 16 + q * 4 + rr;
      float ah = fmaxf(s[rr] + bp, 0.f);
      int rst = rb[(t + 1) * B_DIM + row];
      float am = rst ? 0.f : ah;
      float av = a_all[((size_t)(t + 1) * B_DIM + row) * H_DIM + coln];
      float d = av - am;
      float pos = fmaxf(d, 0.f), neg = fmaxf(-d, 0.f);
      A_next_w[afrag(row, coln, KTC)] = f2bf(pos);
      A_next_w[afrag(row, 1024 + coln, KTC)] = f2bf(neg);
      rsum[rr] = pos + neg;
    }
#pragma unroll
    for (int rr = 0; rr < 4; ++rr) {
      float sv = rsum[rr];
      sv += __shfl_xor(sv, 1);
      sv += __shfl_xor(sv, 2);
      sv += __shfl_xor(sv, 4);
      sv += __shfl_xor(sv, 8);
      if (cl == 0) rsum_red[wave][q][rr] = sv;
    }
  }
  __syncthreads();
  if (wave == 0 && lane < 16) {
    int qq = lane >> 2, rr = lane & 3;
    float sv = rsum_red[0][qq][rr] + rsum_red[1][qq][rr]
             + rsum_red[2][qq][rr] + rsum_red[3][qq][rr];
    int row = mt * 16 + qq * 4 + rr;
    atomicAdd(err_out + (size_t)(t + 1) * B_DIM + row, sv * (1.0f / (float)H_DIM));
  }
}

// ---------------- launch ----------------
extern "C" void kernel_launch(void* const* d_in, const int* in_sizes, int n_in,
                              void* d_out, int out_size, void* d_ws, size_t ws_size,
                              hipStream_t stream) {
  (void)in_sizes; (void)n_in; (void)out_size; (void)ws_size;
  const float* a_all = (const float*)d_in[0];
  const void*  resets = d_in[1];
  const float* W_i  = (const float*)d_in[2];
  const float* b_i  = (const float*)d_in[3];
  const float* W_h  = (const float*)d_in[4];
  const float* b_hn = (const float*)d_in[5];
  const float* W_p  = (const float*)d_in[6];
  const float* b_p  = (const float*)d_in[7];

  float* r_out = (float*)d_out;
  float* err_out = r_out + (size_t)T_DIM * B_DIM * H_DIM;

  char* ws = (char*)d_ws;
  unsigned short* Wg_sw = (unsigned short*)ws; ws += (size_t)256 * 16 * KC * 2;     // 25.2 MB
  unsigned short* Wp_sw = (unsigned short*)ws; ws += (size_t)H_DIM * H_DIM * 2;     // 2 MB
  unsigned short* A0    = (unsigned short*)ws; ws += (size_t)B_DIM * KC * 2;        // 1.5 MB
  unsigned short* A1    = (unsigned short*)ws; ws += (size_t)B_DIM * KC * 2;        // 1.5 MB
  float* h0 = (float*)ws; ws += (size_t)B_DIM * H_DIM * 4;                          // 1 MB
  float* h1 = (float*)ws; ws += (size_t)B_DIM * H_DIM * 4;                          // 1 MB
  unsigned char* rb = (unsigned char*)ws; ws += T_DIM * B_DIM;                      // 32 KB
  int* rflag = (int*)ws; ws += 256;

  hipMemsetAsync(err_out, 0, (size_t)T_DIM * B_DIM * sizeof(float), stream);
  detect_resets<<<1, 256, 0, stream>>>((const int*)resets, rflag);
  decode_resets<<<T_DIM, 256, 0, stream>>>(resets, rflag, rb);
  convert_gates<<<dim3(256, KTC), 256, 0, stream>>>(W_i, W_h, Wg_sw);
  convert_wp<<<dim3(H_DIM / 16, KTP), 256, 0, stream>>>(W_p, Wp_sw);
  init_state<<<B_DIM, 256, 0, stream>>>(a_all, A0, h0, err_out);

  for (int t = 0; t < T_DIM; ++t) {
    const unsigned short* Acur = (t & 1) ? A1 : A0;
    unsigned short* Anext      = (t & 1) ? A0 : A1;
    const float* hcur = (t & 1) ? h1 : h0;
    float* hnext      = (t & 1) ? h0 : h1;
    gates_fused<<<256, 512, 0, stream>>>(
        Acur, Wg_sw, b_i, b_hn, hcur, hnext, Anext, rb, r_out, t);
    if (t < T_DIM - 1)
      pred_fused<<<256, 512, 0, stream>>>(
          Anext, Wp_sw, b_p, a_all, rb, Anext, err_out, t);
  }
}

// Round 19
// 2371.281 us; speedup vs baseline: 1.0392x; 1.0333x over previous
//
#include <hip/hip_runtime.h>
#include <hip/hip_bf16.h>
#include <math.h>

#define T_DIM 128
#define B_DIM 256
#define H_DIM 1024
#define N3    3072
#define KC    3072   // combined K for gates GEMM: 2048 (e) + 1024 (h)
#define KTC   96     // KC/32
#define KTP   32     // H_DIM/32

typedef __attribute__((ext_vector_type(8))) short short8;
typedef __attribute__((ext_vector_type(4))) float float4v;
typedef __attribute__((ext_vector_type(4))) unsigned short ushort4v;

__device__ __forceinline__ unsigned short f2bf(float f) {
  union { float f; unsigned u; } v; v.f = f;
  unsigned u = v.u;
  unsigned r = u + 0x7FFFu + ((u >> 16) & 1u);
  return (unsigned short)(r >> 16);
}

// A-fragment offset for MFMA 16x16x32: lane l holds A[m=16mt+(l&15)][k=32kt+(l>>4)*8+i]
// stored at ((mt*KT + kt)*64 + l)*8 + i
__device__ __forceinline__ size_t afrag(int m, int k, int KT) {
  return ((((size_t)(m >> 4) * KT) + (k >> 5)) * 64
          + ((((k >> 3) & 3) << 4) | (m & 15))) * 8 + (k & 7);
}

__device__ __forceinline__ void store_bf4(unsigned short* p, const float* v) {
  ushort4v u;
  u.x = f2bf(v[0]); u.y = f2bf(v[1]); u.z = f2bf(v[2]); u.w = f2bf(v[3]);
  *(ushort4v*)p = u;
}

// fast transcendentals for the GRU epilogue (serial tail):
// raw v_rcp (~2.5e-7 rel err) + v_exp; tanh saturates correctly via inf/0.
__device__ __forceinline__ float fast_rcp(float x) { return __builtin_amdgcn_rcpf(x); }
__device__ __forceinline__ float sigm(float x) { return fast_rcp(1.f + __expf(-x)); }
__device__ __forceinline__ float tanh_fast(float x) {
  return 1.f - 2.f * fast_rcp(__expf(2.f * x) + 1.f);
}

// async global->LDS, 16 B/lane. gsrc is per-lane; ldst must be wave-uniform
// (HW writes lane data at ldst + lane*16).
__device__ __forceinline__ void glds16(const void* gsrc, void* ldst) {
  __builtin_amdgcn_global_load_lds(
      (const __attribute__((address_space(1))) unsigned int*)gsrc,
      (__attribute__((address_space(3))) unsigned int*)ldst, 16, 0, 0);
}

// ---------------- resets dtype detection + decode ----------------
__global__ void detect_resets(const int* __restrict__ r, int* __restrict__ flag) {
  __shared__ int f;
  if (threadIdx.x == 0) f = 0;
  __syncthreads();
  int loc = 0;
  for (int i = threadIdx.x; i < 8192; i += 256) {
    if ((unsigned)r[i] > 1u) loc = 1;
  }
  if (loc) f = 1;
  __syncthreads();
  if (threadIdx.x == 0) *flag = f;
}

__global__ __launch_bounds__(256) void decode_resets(
    const void* __restrict__ resets, const int* __restrict__ rflag,
    unsigned char* __restrict__ rb) {
  int t = blockIdx.x, b = threadIdx.x;
  int v;
  if (*rflag) v = (int)((const unsigned char*)resets)[t * B_DIM + b];
  else        v = ((const int*)resets)[t * B_DIM + b];
  rb[t * B_DIM + b] = (v != 0) ? 1 : 0;
}

// ---------------- weight conversion ----------------
// Gates weights, virtual N = 64 jt * 4 groups * 16 cols. group g:
//   0 = r, 1 = z (Wi rows k<2048 | Wh rows k>=2048), 2 = n_i (k<2048), 3 = n_h (k>=2048)
__global__ __launch_bounds__(256) void convert_gates(
    const float* __restrict__ Wi, const float* __restrict__ Wh,
    unsigned short* __restrict__ Wg) {
  int nt = blockIdx.x;   // 0..255
  int kt = blockIdx.y;   // 0..95
  int jt = nt >> 2, g = nt & 3;
  size_t base = ((size_t)nt * KTC + kt) * 512;
  for (int e = threadIdx.x; e < 512; e += 256) {
    int i = e & 7, l = (e >> 3) & 63;
    int k = (kt << 5) + ((l >> 4) << 3) + i;
    int j = (jt << 4) + (l & 15);
    float v = 0.f;
    if (g == 0) v = (k < 2048) ? Wi[(size_t)k * N3 + j] : Wh[(size_t)(k - 2048) * N3 + j];
    else if (g == 1) v = (k < 2048) ? Wi[(size_t)k * N3 + 1024 + j] : Wh[(size_t)(k - 2048) * N3 + 1024 + j];
    else if (g == 2) { if (k < 2048) v = Wi[(size_t)k * N3 + 2048 + j]; }
    else             { if (k >= 2048) v = Wh[(size_t)(k - 2048) * N3 + 2048 + j]; }
    Wg[base + e] = f2bf(v);
  }
}

__global__ __launch_bounds__(256) void convert_wp(const float* __restrict__ W,
                                                  unsigned short* __restrict__ Wsw) {
  int nt = blockIdx.x;   // 0..63
  int kt = blockIdx.y;   // 0..31
  size_t base = ((size_t)nt * KTP + kt) * 512;
  for (int e = threadIdx.x; e < 512; e += 256) {
    int i = e & 7, l = (e >> 3) & 63;
    int k = (kt << 5) + ((l >> 4) << 3) + i;
    int n = (nt << 4) + (l & 15);
    Wsw[base + e] = f2bf(W[(size_t)k * H_DIM + n]);
  }
}

// ---------------- init (t = 0 state) ----------------
__global__ __launch_bounds__(256) void init_state(
    const float* __restrict__ a_all,
    unsigned short* __restrict__ A0, float* __restrict__ h0,
    float* __restrict__ err_out) {
  int b = blockIdx.x, tid = threadIdx.x;
  int j0 = tid * 4;
  const float* arow = a_all + (size_t)b * H_DIM;
  float pv[4], nv[4], zz[4] = {0.f, 0.f, 0.f, 0.f};
  float s = 0.f;
#pragma unroll
  for (int jj = 0; jj < 4; ++jj) {
    float a = arow[j0 + jj];
    pv[jj] = fmaxf(a, 0.f);
    nv[jj] = fmaxf(-a, 0.f);
    s += pv[jj] + nv[jj];
    h0[(size_t)b * H_DIM + j0 + jj] = 0.f;
  }
  store_bf4(A0 + afrag(b, j0, KTC), pv);
  store_bf4(A0 + afrag(b, 1024 + j0, KTC), nv);
  store_bf4(A0 + afrag(b, 2048 + j0, KTC), zz);
  __shared__ float red[256];
  red[tid] = s;
  __syncthreads();
  for (int st = 128; st > 0; st >>= 1) {
    if (tid < st) red[tid] += red[tid + st];
    __syncthreads();
  }
  if (tid == 0) err_out[b] = red[0] * (1.0f / (float)H_DIM);
}

// ---------------- fused gates GEMM + GRU update (global_load_lds pipeline) ----------------
// grid 256 (1 block/CU), 512 threads = 8 waves. Block b: jt = b & 63 (XCD-pinned
// weight slice: XCD = b%8 = jt%8), rg2 = b >> 6 (64 rows = 4 m-tiles).
// Wave w owns kt = 8c + w, c = 0..11 (12 kt). Per chunk: 7 async
// global_load_lds (4 A + 3 W, 1 KB each) into the wave's PRIVATE double-buffered
// LDS slot; counted s_waitcnt vmcnt(7) (never 0 until drain); 7 ds_read_b128;
// 12 MFMA. No barriers in the k-loop (wave-private data). c<8 = e-part (n_i,
// GS=2), c>=8 = h-part (n_h, GS=3) — uniform per chunk for every wave.
// After the loop: __syncthreads, then the stage LDS is overlaid by the
// two-stage reduce + GRU epilogue (fast-transcendental tail).
__global__ __launch_bounds__(512, 1) void gates_fused(
    const unsigned short* __restrict__ A_sw, const unsigned short* __restrict__ Wg,
    const float* __restrict__ b_i, const float* __restrict__ b_hn,
    const float* __restrict__ h_in, float* __restrict__ h_out,
    unsigned short* __restrict__ A_next,
    const unsigned char* __restrict__ rb,
    float* __restrict__ r_out, int t) {
  int lane = threadIdx.x & 63, wave = threadIdx.x >> 6;
  int b = blockIdx.x;
  int jt = b & 63;
  int rg2 = b >> 6;   // 0..3

  __shared__ short8 stage[2][8][7][64];   // 112 KB: [buf][wave][frag][lane]

  const short8* A8 = (const short8*)A_sw;
  const short8* B8 = (const short8*)Wg;

  // global fragment bases (short8 units, without lane)
  const short8* aB0 = A8 + ((size_t)(rg2 * 4 + 0) * KTC) * 64;
  const short8* aB1 = A8 + ((size_t)(rg2 * 4 + 1) * KTC) * 64;
  const short8* aB2 = A8 + ((size_t)(rg2 * 4 + 2) * KTC) * 64;
  const short8* aB3 = A8 + ((size_t)(rg2 * 4 + 3) * KTC) * 64;
  const short8* wBr = B8 + ((size_t)(jt * 4 + 0) * KTC) * 64;
  const short8* wBz = B8 + ((size_t)(jt * 4 + 1) * KTC) * 64;
  const short8* wBi = B8 + ((size_t)(jt * 4 + 2) * KTC) * 64;
  const short8* wBh = B8 + ((size_t)(jt * 4 + 3) * KTC) * 64;

  float4v acc[4][4];
#pragma unroll
  for (int mi = 0; mi < 4; ++mi)
#pragma unroll
    for (int g = 0; g < 4; ++g) acc[mi][g] = (float4v){0.f, 0.f, 0.f, 0.f};

  // stage chunk cc (kt = 8*cc + wave) into buffer cc&1. A first (IC latency).
#define STAGE_CHUNK(cc, NSRC)                                                  \
  {                                                                            \
    int kt_ = 8 * (cc) + wave;                                                 \
    size_t o_ = (size_t)kt_ * 64 + lane;                                       \
    short8* d_ = &stage[(cc) & 1][wave][0][0];                                 \
    glds16((const void*)(aB0 + o_), (void*)(d_ + 0 * 64));                     \
    glds16((const void*)(aB1 + o_), (void*)(d_ + 1 * 64));                     \
    glds16((const void*)(aB2 + o_), (void*)(d_ + 2 * 64));                     \
    glds16((const void*)(aB3 + o_), (void*)(d_ + 3 * 64));                     \
    glds16((const void*)(wBr + o_), (void*)(d_ + 4 * 64));                     \
    glds16((const void*)(wBz + o_), (void*)(d_ + 5 * 64));                     \
    glds16((const void*)(NSRC + o_), (void*)(d_ + 6 * 64));                    \
  }

  STAGE_CHUNK(0, wBi);   // prologue: chunk 0 in flight (7 loads)

#pragma unroll
  for (int c = 0; c < 12; ++c) {
    if (c < 11) {
      if (c + 1 < 8) STAGE_CHUNK(c + 1, wBi)
      else           STAGE_CHUNK(c + 1, wBh)
      asm volatile("s_waitcnt vmcnt(7)" ::: "memory");   // chunk c landed
    } else {
      asm volatile("s_waitcnt vmcnt(0)" ::: "memory");   // drain last chunk
    }
    __builtin_amdgcn_sched_barrier(0);

    const short8* f = &stage[c & 1][wave][0][0];
    short8 A0f = f[0 * 64 + lane];
    short8 A1f = f[1 * 64 + lane];
    short8 A2f = f[2 * 64 + lane];
    short8 A3f = f[3 * 64 + lane];
    short8 Rf  = f[4 * 64 + lane];
    short8 Zf  = f[5 * 64 + lane];
    short8 Nf  = f[6 * 64 + lane];

    const int GS = (c < 8) ? 2 : 3;   // static after unroll
    acc[0][0]  = __builtin_amdgcn_mfma_f32_16x16x32_bf16(A0f, Rf, acc[0][0], 0, 0, 0);
    acc[1][0]  = __builtin_amdgcn_mfma_f32_16x16x32_bf16(A1f, Rf, acc[1][0], 0, 0, 0);
    acc[2][0]  = __builtin_amdgcn_mfma_f32_16x16x32_bf16(A2f, Rf, acc[2][0], 0, 0, 0);
    acc[3][0]  = __builtin_amdgcn_mfma_f32_16x16x32_bf16(A3f, Rf, acc[3][0], 0, 0, 0);
    acc[0][1]  = __builtin_amdgcn_mfma_f32_16x16x32_bf16(A0f, Zf, acc[0][1], 0, 0, 0);
    acc[1][1]  = __builtin_amdgcn_mfma_f32_16x16x32_bf16(A1f, Zf, acc[1][1], 0, 0, 0);
    acc[2][1]  = __builtin_amdgcn_mfma_f32_16x16x32_bf16(A2f, Zf, acc[2][1], 0, 0, 0);
    acc[3][1]  = __builtin_amdgcn_mfma_f32_16x16x32_bf16(A3f, Zf, acc[3][1], 0, 0, 0);
    acc[0][GS] = __builtin_amdgcn_mfma_f32_16x16x32_bf16(A0f, Nf, acc[0][GS], 0, 0, 0);
    acc[1][GS] = __builtin_amdgcn_mfma_f32_16x16x32_bf16(A1f, Nf, acc[1][GS], 0, 0, 0);
    acc[2][GS] = __builtin_amdgcn_mfma_f32_16x16x32_bf16(A2f, Nf, acc[2][GS], 0, 0, 0);
    acc[3][GS] = __builtin_amdgcn_mfma_f32_16x16x32_bf16(A3f, Nf, acc[3][GS], 0, 0, 0);
  }
#undef STAGE_CHUNK

  __syncthreads();   // all waves done with stage LDS; overlay reduce buffer

  // two-stage reduce, red overlays stage: [4][4][2][64] float4v
  float4v (*red)[4][2][64] = (float4v (*)[4][2][64])(&stage[0][0][0][0]);

#pragma unroll
  for (int hh = 0; hh < 2; ++hh) {
    if (wave >= 4) {
#pragma unroll
      for (int mi = 0; mi < 4; ++mi) {
        red[wave - 4][mi][0][lane] = acc[mi][2 * hh];
        red[wave - 4][mi][1][lane] = acc[mi][2 * hh + 1];
      }
    }
    __syncthreads();
    if (wave < 4) {
#pragma unroll
      for (int mi = 0; mi < 4; ++mi) {
        acc[mi][2 * hh]     += red[wave][mi][0][lane];
        acc[mi][2 * hh + 1] += red[wave][mi][1][lane];
      }
    }
    __syncthreads();
  }
  float4v accs[4];
#pragma unroll
  for (int hh = 0; hh < 2; ++hh) {
    if (wave < 4) {
#pragma unroll
      for (int mi = 0; mi < 4; ++mi) {
        red[wave][mi][0][lane] = acc[mi][2 * hh];
        red[wave][mi][1][lane] = acc[mi][2 * hh + 1];
      }
    }
    __syncthreads();
    if (wave < 4) {
      float4v s0 = red[0][wave][0][lane];
      float4v s1 = red[0][wave][1][lane];
#pragma unroll
      for (int w = 1; w < 4; ++w) {
        s0 += red[w][wave][0][lane];
        s1 += red[w][wave][1][lane];
      }
      accs[2 * hh] = s0; accs[2 * hh + 1] = s1;
    }
    __syncthreads();
  }

  // GRU epilogue (waves 0-3, 16 rows x 16 cols each) — fast transcendentals
  if (wave < 4) {
    int cl = lane & 15, q = lane >> 4;
    int jcol = (jt << 4) + cl;
    float br_ = b_i[jcol], bz_ = b_i[1024 + jcol], bn_ = b_i[2048 + jcol];
    float bh = b_hn[jcol];
    int row_base = rg2 * 64 + wave * 16 + q * 4;
#pragma unroll
    for (int rr = 0; rr < 4; ++rr) {
      int row = row_base + rr;
      float r = sigm(accs[0][rr] + br_);
      float z = sigm(accs[1][rr] + bz_);
      float n = tanh_fast(accs[2][rr] + bn_ + r * (accs[3][rr] + bh));
      float hv = h_in[(size_t)row * H_DIM + jcol];
      float nh = (1.f - z) * n + z * hv;
      r_out[((size_t)t * B_DIM + row) * H_DIM + jcol] = nh;
      if (t < T_DIM - 1) {
        int rst = rb[(t + 1) * B_DIM + row];
        float hm = rst ? 0.f : nh;
        h_out[(size_t)row * H_DIM + jcol] = hm;
        A_next[afrag(row, 2048 + jcol, KTC)] = f2bf(hm);  // pred + next gates read this
      }
    }
  }
}

// ---------------- fused pred GEMM + e_t / err for step t+1 ----------------
__global__ __launch_bounds__(512, 2) void pred_fused(
    const unsigned short* __restrict__ A_next, const unsigned short* __restrict__ Wp,
    const float* __restrict__ b_p, const float* __restrict__ a_all,
    const unsigned char* __restrict__ rb,
    unsigned short* __restrict__ A_next_w, float* __restrict__ err_out, int t) {
  int lane = threadIdx.x & 63, wave = threadIdx.x >> 6;
  int b = blockIdx.x;
  int ntq = b & 15, mt = b >> 4;

  const short8* A8 = (const short8*)A_next;
  const short8* B8 = (const short8*)Wp;

  const short8* hap = A8 + ((size_t)mt * KTC + 64) * 64 + lane;
  const short8* bp0 = B8 + ((size_t)(ntq * 4 + 0) * KTP) * 64 + lane;
  const short8* bp1 = B8 + ((size_t)(ntq * 4 + 1) * KTP) * 64 + lane;
  const short8* bp2 = B8 + ((size_t)(ntq * 4 + 2) * KTP) * 64 + lane;
  const short8* bp3 = B8 + ((size_t)(ntq * 4 + 3) * KTP) * 64 + lane;

  float4v acc[4];
#pragma unroll
  for (int n = 0; n < 4; ++n) acc[n] = (float4v){0.f, 0.f, 0.f, 0.f};

  {
    int pk0 = wave * 4;   // 8 waves x 4 kt = 32 kt
    short8 Aa[4], B0a[4], B1a[4], B2a[4], B3a[4];
#pragma unroll
    for (int kk = 0; kk < 4; ++kk) Aa[kk] = hap[(size_t)(pk0 + kk) * 64];
#pragma unroll
    for (int kk = 0; kk < 4; ++kk) {
      size_t o = (size_t)(pk0 + kk) * 64;
      B0a[kk] = bp0[o]; B1a[kk] = bp1[o]; B2a[kk] = bp2[o]; B3a[kk] = bp3[o];
    }
#pragma unroll
    for (int kk = 0; kk < 4; ++kk) {
      acc[0] = __builtin_amdgcn_mfma_f32_16x16x32_bf16(Aa[kk], B0a[kk], acc[0], 0, 0, 0);
      acc[1] = __builtin_amdgcn_mfma_f32_16x16x32_bf16(Aa[kk], B1a[kk], acc[1], 0, 0, 0);
      acc[2] = __builtin_amdgcn_mfma_f32_16x16x32_bf16(Aa[kk], B2a[kk], acc[2], 0, 0, 0);
      acc[3] = __builtin_amdgcn_mfma_f32_16x16x32_bf16(Aa[kk], B3a[kk], acc[3], 0, 0, 0);
    }
  }

  __shared__ float4v red[8][4][64];        // 32 KB
  __shared__ float rsum_red[4][4][4];
#pragma unroll
  for (int n = 0; n < 4; ++n) red[wave][n][lane] = acc[n];
  __syncthreads();

  int cl = lane & 15, q = lane >> 4;

  if (wave < 4) {
    float4v s = red[0][wave][lane];
#pragma unroll
    for (int w = 1; w < 8; ++w) s += red[w][wave][lane];

    int coln = (ntq * 4 + wave) * 16 + cl;
    float bp = b_p[coln];
    float rsum[4];
#pragma unroll
    for (int rr = 0; rr < 4; ++rr) {
      int row = mt * 16 + q * 4 + rr;
      float ah = fmaxf(s[rr] + bp, 0.f);
      int rst = rb[(t + 1) * B_DIM + row];
      float am = rst ? 0.f : ah;
      float av = a_all[((size_t)(t + 1) * B_DIM + row) * H_DIM + coln];
      float d = av - am;
      float pos = fmaxf(d, 0.f), neg = fmaxf(-d, 0.f);
      A_next_w[afrag(row, coln, KTC)] = f2bf(pos);
      A_next_w[afrag(row, 1024 + coln, KTC)] = f2bf(neg);
      rsum[rr] = pos + neg;
    }
#pragma unroll
    for (int rr = 0; rr < 4; ++rr) {
      float sv = rsum[rr];
      sv += __shfl_xor(sv, 1);
      sv += __shfl_xor(sv, 2);
      sv += __shfl_xor(sv, 4);
      sv += __shfl_xor(sv, 8);
      if (cl == 0) rsum_red[wave][q][rr] = sv;
    }
  }
  __syncthreads();
  if (wave == 0 && lane < 16) {
    int qq = lane >> 2, rr = lane & 3;
    float sv = rsum_red[0][qq][rr] + rsum_red[1][qq][rr]
             + rsum_red[2][qq][rr] + rsum_red[3][qq][rr];
    int row = mt * 16 + qq * 4 + rr;
    atomicAdd(err_out + (size_t)(t + 1) * B_DIM + row, sv * (1.0f / (float)H_DIM));
  }
}

// ---------------- launch ----------------
extern "C" void kernel_launch(void* const* d_in, const int* in_sizes, int n_in,
                              void* d_out, int out_size, void* d_ws, size_t ws_size,
                              hipStream_t stream) {
  (void)in_sizes; (void)n_in; (void)out_size; (void)ws_size;
  const float* a_all = (const float*)d_in[0];
  const void*  resets = d_in[1];
  const float* W_i  = (const float*)d_in[2];
  const float* b_i  = (const float*)d_in[3];
  const float* W_h  = (const float*)d_in[4];
  const float* b_hn = (const float*)d_in[5];
  const float* W_p  = (const float*)d_in[6];
  const float* b_p  = (const float*)d_in[7];

  float* r_out = (float*)d_out;
  float* err_out = r_out + (size_t)T_DIM * B_DIM * H_DIM;

  char* ws = (char*)d_ws;
  unsigned short* Wg_sw = (unsigned short*)ws; ws += (size_t)256 * 16 * KC * 2;     // 25.2 MB
  unsigned short* Wp_sw = (unsigned short*)ws; ws += (size_t)H_DIM * H_DIM * 2;     // 2 MB
  unsigned short* A0    = (unsigned short*)ws; ws += (size_t)B_DIM * KC * 2;        // 1.5 MB
  unsigned short* A1    = (unsigned short*)ws; ws += (size_t)B_DIM * KC * 2;        // 1.5 MB
  float* h0 = (float*)ws; ws += (size_t)B_DIM * H_DIM * 4;                          // 1 MB
  float* h1 = (float*)ws; ws += (size_t)B_DIM * H_DIM * 4;                          // 1 MB
  unsigned char* rb = (unsigned char*)ws; ws += T_DIM * B_DIM;                      // 32 KB
  int* rflag = (int*)ws; ws += 256;

  hipMemsetAsync(err_out, 0, (size_t)T_DIM * B_DIM * sizeof(float), stream);
  detect_resets<<<1, 256, 0, stream>>>((const int*)resets, rflag);
  decode_resets<<<T_DIM, 256, 0, stream>>>(resets, rflag, rb);
  convert_gates<<<dim3(256, KTC), 256, 0, stream>>>(W_i, W_h, Wg_sw);
  convert_wp<<<dim3(H_DIM / 16, KTP), 256, 0, stream>>>(W_p, Wp_sw);
  init_state<<<B_DIM, 256, 0, stream>>>(a_all, A0, h0, err_out);

  for (int t = 0; t < T_DIM; ++t) {
    const unsigned short* Acur = (t & 1) ? A1 : A0;
    unsigned short* Anext      = (t & 1) ? A0 : A1;
    const float* hcur = (t & 1) ? h1 : h0;
    float* hnext      = (t & 1) ? h0 : h1;
    gates_fused<<<256, 512, 0, stream>>>(
        Acur, Wg_sw, b_i, b_hn, hcur, hnext, Anext, rb, r_out, t);
    if (t < T_DIM - 1)
      pred_fused<<<256, 512, 0, stream>>>(
          Anext, Wp_sw, b_p, a_all, rb, Anext, err_out, t);
  }
}

// Round 20
// 2289.187 us; speedup vs baseline: 1.0765x; 1.0359x over previous
//
#include <hip/hip_runtime.h>
#include <hip/hip_bf16.h>
#include <math.h>

#define T_DIM 128
#define B_DIM 256
#define H_DIM 1024
#define N3    3072
#define KC    3072   // combined K for gates GEMM: 2048 (e) + 1024 (h)
#define KTC   96     // KC/32
#define KTP   32     // H_DIM/32

typedef __attribute__((ext_vector_type(8))) short short8;
typedef __attribute__((ext_vector_type(4))) float float4v;
typedef __attribute__((ext_vector_type(2))) float float2v;
typedef __attribute__((ext_vector_type(4))) unsigned short ushort4v;

__device__ __forceinline__ unsigned short f2bf(float f) {
  union { float f; unsigned u; } v; v.f = f;
  unsigned u = v.u;
  unsigned r = u + 0x7FFFu + ((u >> 16) & 1u);
  return (unsigned short)(r >> 16);
}

// A-fragment offset for MFMA 16x16x32: lane l holds A[m=16mt+(l&15)][k=32kt+(l>>4)*8+i]
// stored at ((mt*KT + kt)*64 + l)*8 + i
__device__ __forceinline__ size_t afrag(int m, int k, int KT) {
  return ((((size_t)(m >> 4) * KT) + (k >> 5)) * 64
          + ((((k >> 3) & 3) << 4) | (m & 15))) * 8 + (k & 7);
}

__device__ __forceinline__ void store_bf4(unsigned short* p, const float* v) {
  ushort4v u;
  u.x = f2bf(v[0]); u.y = f2bf(v[1]); u.z = f2bf(v[2]); u.w = f2bf(v[3]);
  *(ushort4v*)p = u;
}

// fast transcendentals for the GRU epilogue (serial tail):
// raw v_rcp (~2.5e-7 rel err) + v_exp; tanh saturates correctly via inf/0.
__device__ __forceinline__ float fast_rcp(float x) { return __builtin_amdgcn_rcpf(x); }
__device__ __forceinline__ float sigm(float x) { return fast_rcp(1.f + __expf(-x)); }
__device__ __forceinline__ float tanh_fast(float x) {
  return 1.f - 2.f * fast_rcp(__expf(2.f * x) + 1.f);
}

// async global->LDS, 16 B/lane. gsrc is per-lane; ldst must be wave-uniform
// (HW writes lane data at ldst + lane*16).
__device__ __forceinline__ void glds16(const void* gsrc, void* ldst) {
  __builtin_amdgcn_global_load_lds(
      (const __attribute__((address_space(1))) unsigned int*)gsrc,
      (__attribute__((address_space(3))) unsigned int*)ldst, 16, 0, 0);
}

// ---------------- resets dtype detection + decode ----------------
__global__ void detect_resets(const int* __restrict__ r, int* __restrict__ flag) {
  __shared__ int f;
  if (threadIdx.x == 0) f = 0;
  __syncthreads();
  int loc = 0;
  for (int i = threadIdx.x; i < 8192; i += 256) {
    if ((unsigned)r[i] > 1u) loc = 1;
  }
  if (loc) f = 1;
  __syncthreads();
  if (threadIdx.x == 0) *flag = f;
}

__global__ __launch_bounds__(256) void decode_resets(
    const void* __restrict__ resets, const int* __restrict__ rflag,
    unsigned char* __restrict__ rb) {
  int t = blockIdx.x, b = threadIdx.x;
  int v;
  if (*rflag) v = (int)((const unsigned char*)resets)[t * B_DIM + b];
  else        v = ((const int*)resets)[t * B_DIM + b];
  rb[t * B_DIM + b] = (v != 0) ? 1 : 0;
}

// ---------------- weight conversion ----------------
// Gates weights, virtual N = 64 jt * 4 groups * 16 cols. group g:
//   0 = r, 1 = z (Wi rows k<2048 | Wh rows k>=2048), 2 = n_i (k<2048), 3 = n_h (k>=2048)
__global__ __launch_bounds__(256) void convert_gates(
    const float* __restrict__ Wi, const float* __restrict__ Wh,
    unsigned short* __restrict__ Wg) {
  int nt = blockIdx.x;   // 0..255
  int kt = blockIdx.y;   // 0..95
  int jt = nt >> 2, g = nt & 3;
  size_t base = ((size_t)nt * KTC + kt) * 512;
  for (int e = threadIdx.x; e < 512; e += 256) {
    int i = e & 7, l = (e >> 3) & 63;
    int k = (kt << 5) + ((l >> 4) << 3) + i;
    int j = (jt << 4) + (l & 15);
    float v = 0.f;
    if (g == 0) v = (k < 2048) ? Wi[(size_t)k * N3 + j] : Wh[(size_t)(k - 2048) * N3 + j];
    else if (g == 1) v = (k < 2048) ? Wi[(size_t)k * N3 + 1024 + j] : Wh[(size_t)(k - 2048) * N3 + 1024 + j];
    else if (g == 2) { if (k < 2048) v = Wi[(size_t)k * N3 + 2048 + j]; }
    else             { if (k >= 2048) v = Wh[(size_t)(k - 2048) * N3 + 2048 + j]; }
    Wg[base + e] = f2bf(v);
  }
}

__global__ __launch_bounds__(256) void convert_wp(const float* __restrict__ W,
                                                  unsigned short* __restrict__ Wsw) {
  int nt = blockIdx.x;   // 0..63
  int kt = blockIdx.y;   // 0..31
  size_t base = ((size_t)nt * KTP + kt) * 512;
  for (int e = threadIdx.x; e < 512; e += 256) {
    int i = e & 7, l = (e >> 3) & 63;
    int k = (kt << 5) + ((l >> 4) << 3) + i;
    int n = (nt << 4) + (l & 15);
    Wsw[base + e] = f2bf(W[(size_t)k * H_DIM + n]);
  }
}

// ---------------- init (t = 0 state) ----------------
__global__ __launch_bounds__(256) void init_state(
    const float* __restrict__ a_all,
    unsigned short* __restrict__ A0, float* __restrict__ h0,
    float* __restrict__ err_out) {
  int b = blockIdx.x, tid = threadIdx.x;
  int j0 = tid * 4;
  const float* arow = a_all + (size_t)b * H_DIM;
  float pv[4], nv[4], zz[4] = {0.f, 0.f, 0.f, 0.f};
  float s = 0.f;
#pragma unroll
  for (int jj = 0; jj < 4; ++jj) {
    float a = arow[j0 + jj];
    pv[jj] = fmaxf(a, 0.f);
    nv[jj] = fmaxf(-a, 0.f);
    s += pv[jj] + nv[jj];
    h0[(size_t)b * H_DIM + j0 + jj] = 0.f;
  }
  store_bf4(A0 + afrag(b, j0, KTC), pv);
  store_bf4(A0 + afrag(b, 1024 + j0, KTC), nv);
  store_bf4(A0 + afrag(b, 2048 + j0, KTC), zz);
  __shared__ float red[256];
  red[tid] = s;
  __syncthreads();
  for (int st = 128; st > 0; st >>= 1) {
    if (tid < st) red[tid] += red[tid + st];
    __syncthreads();
  }
  if (tid == 0) err_out[b] = red[0] * (1.0f / (float)H_DIM);
}

// ---------------- fused gates GEMM + GRU update (global_load_lds pipeline) ----------------
// grid 256 (1 block/CU), 512 threads = 8 waves. Block b: jt = b & 63 (XCD-pinned
// weight slice: XCD = b%8 = jt%8), rg2 = b >> 6 (64 rows = 4 m-tiles).
// Wave w owns kt = 8c + w, c = 0..11 (12 kt). Per chunk: 7 async
// global_load_lds (4 A + 3 W, 1 KB each) into the wave's PRIVATE double-buffered
// LDS slot; counted s_waitcnt vmcnt(7) (never 0 until drain); 7 ds_read_b128;
// 12 MFMA. No barriers in the k-loop (wave-private data).
// After the loop: 4-barrier flat reduce (8-wave deposit per g-half into a 64 KB
// overlay of the stage LDS), early h_in prefetch, GRU epilogue with packed
// (f32x2 / bf16x2) state stores and fast transcendentals.
__global__ __launch_bounds__(512, 1) void gates_fused(
    const unsigned short* __restrict__ A_sw, const unsigned short* __restrict__ Wg,
    const float* __restrict__ b_i, const float* __restrict__ b_hn,
    const float* __restrict__ h_in, float* __restrict__ h_out,
    unsigned short* __restrict__ A_next,
    const unsigned char* __restrict__ rb,
    float* __restrict__ r_out, int t) {
  int lane = threadIdx.x & 63, wave = threadIdx.x >> 6;
  int b = blockIdx.x;
  int jt = b & 63;
  int rg2 = b >> 6;   // 0..3

  __shared__ short8 stage[2][8][7][64];   // 112 KB: [buf][wave][frag][lane]

  const short8* A8 = (const short8*)A_sw;
  const short8* B8 = (const short8*)Wg;

  // global fragment bases (short8 units, without lane)
  const short8* aB0 = A8 + ((size_t)(rg2 * 4 + 0) * KTC) * 64;
  const short8* aB1 = A8 + ((size_t)(rg2 * 4 + 1) * KTC) * 64;
  const short8* aB2 = A8 + ((size_t)(rg2 * 4 + 2) * KTC) * 64;
  const short8* aB3 = A8 + ((size_t)(rg2 * 4 + 3) * KTC) * 64;
  const short8* wBr = B8 + ((size_t)(jt * 4 + 0) * KTC) * 64;
  const short8* wBz = B8 + ((size_t)(jt * 4 + 1) * KTC) * 64;
  const short8* wBi = B8 + ((size_t)(jt * 4 + 2) * KTC) * 64;
  const short8* wBh = B8 + ((size_t)(jt * 4 + 3) * KTC) * 64;

  float4v acc[4][4];
#pragma unroll
  for (int mi = 0; mi < 4; ++mi)
#pragma unroll
    for (int g = 0; g < 4; ++g) acc[mi][g] = (float4v){0.f, 0.f, 0.f, 0.f};

  // stage chunk cc (kt = 8*cc + wave) into buffer cc&1. A first (IC latency).
#define STAGE_CHUNK(cc, NSRC)                                                  \
  {                                                                            \
    int kt_ = 8 * (cc) + wave;                                                 \
    size_t o_ = (size_t)kt_ * 64 + lane;                                       \
    short8* d_ = &stage[(cc) & 1][wave][0][0];                                 \
    glds16((const void*)(aB0 + o_), (void*)(d_ + 0 * 64));                     \
    glds16((const void*)(aB1 + o_), (void*)(d_ + 1 * 64));                     \
    glds16((const void*)(aB2 + o_), (void*)(d_ + 2 * 64));                     \
    glds16((const void*)(aB3 + o_), (void*)(d_ + 3 * 64));                     \
    glds16((const void*)(wBr + o_), (void*)(d_ + 4 * 64));                     \
    glds16((const void*)(wBz + o_), (void*)(d_ + 5 * 64));                     \
    glds16((const void*)(NSRC + o_), (void*)(d_ + 6 * 64));                    \
  }

  STAGE_CHUNK(0, wBi);   // prologue: chunk 0 in flight (7 loads)

#pragma unroll
  for (int c = 0; c < 12; ++c) {
    if (c < 11) {
      if (c + 1 < 8) STAGE_CHUNK(c + 1, wBi)
      else           STAGE_CHUNK(c + 1, wBh)
      asm volatile("s_waitcnt vmcnt(7)" ::: "memory");   // chunk c landed
    } else {
      asm volatile("s_waitcnt vmcnt(0)" ::: "memory");   // drain last chunk
    }
    __builtin_amdgcn_sched_barrier(0);

    const short8* f = &stage[c & 1][wave][0][0];
    short8 A0f = f[0 * 64 + lane];
    short8 A1f = f[1 * 64 + lane];
    short8 A2f = f[2 * 64 + lane];
    short8 A3f = f[3 * 64 + lane];
    short8 Rf  = f[4 * 64 + lane];
    short8 Zf  = f[5 * 64 + lane];
    short8 Nf  = f[6 * 64 + lane];

    const int GS = (c < 8) ? 2 : 3;   // static after unroll
    acc[0][0]  = __builtin_amdgcn_mfma_f32_16x16x32_bf16(A0f, Rf, acc[0][0], 0, 0, 0);
    acc[1][0]  = __builtin_amdgcn_mfma_f32_16x16x32_bf16(A1f, Rf, acc[1][0], 0, 0, 0);
    acc[2][0]  = __builtin_amdgcn_mfma_f32_16x16x32_bf16(A2f, Rf, acc[2][0], 0, 0, 0);
    acc[3][0]  = __builtin_amdgcn_mfma_f32_16x16x32_bf16(A3f, Rf, acc[3][0], 0, 0, 0);
    acc[0][1]  = __builtin_amdgcn_mfma_f32_16x16x32_bf16(A0f, Zf, acc[0][1], 0, 0, 0);
    acc[1][1]  = __builtin_amdgcn_mfma_f32_16x16x32_bf16(A1f, Zf, acc[1][1], 0, 0, 0);
    acc[2][1]  = __builtin_amdgcn_mfma_f32_16x16x32_bf16(A2f, Zf, acc[2][1], 0, 0, 0);
    acc[3][1]  = __builtin_amdgcn_mfma_f32_16x16x32_bf16(A3f, Zf, acc[3][1], 0, 0, 0);
    acc[0][GS] = __builtin_amdgcn_mfma_f32_16x16x32_bf16(A0f, Nf, acc[0][GS], 0, 0, 0);
    acc[1][GS] = __builtin_amdgcn_mfma_f32_16x16x32_bf16(A1f, Nf, acc[1][GS], 0, 0, 0);
    acc[2][GS] = __builtin_amdgcn_mfma_f32_16x16x32_bf16(A2f, Nf, acc[2][GS], 0, 0, 0);
    acc[3][GS] = __builtin_amdgcn_mfma_f32_16x16x32_bf16(A3f, Nf, acc[3][GS], 0, 0, 0);
  }
#undef STAGE_CHUNK

  __syncthreads();   // #1: all waves done with stage LDS; overlay reduce buffer

  int cl = lane & 15, q = lane >> 4;
  int jcol = (jt << 4) + cl;
  int row_base = rg2 * 64 + wave * 16 + q * 4;

  // early h prefetch: hide h_in latency under the reduce barriers
  float hv4[4];
  if (wave < 4) {
#pragma unroll
    for (int rr = 0; rr < 4; ++rr)
      hv4[rr] = h_in[(size_t)(row_base + rr) * H_DIM + jcol];
  }

  // flat reduce: 64 KB overlay [8 waves][4 mi][2 g-of-half][64 lanes]
  float4v (*red)[4][2][64] = (float4v (*)[4][2][64])(&stage[0][0][0][0]);
  float4v accs[4];
#pragma unroll
  for (int hh = 0; hh < 2; ++hh) {
#pragma unroll
    for (int mi = 0; mi < 4; ++mi) {
      red[wave][mi][0][lane] = acc[mi][2 * hh];
      red[wave][mi][1][lane] = acc[mi][2 * hh + 1];
    }
    __syncthreads();   // #2 / #4: deposits visible
    if (wave < 4) {
      float4v s0 = red[0][wave][0][lane];
      float4v s1 = red[0][wave][1][lane];
#pragma unroll
      for (int w = 1; w < 8; ++w) {
        s0 += red[w][wave][0][lane];
        s1 += red[w][wave][1][lane];
      }
      accs[2 * hh] = s0; accs[2 * hh + 1] = s1;
    }
    if (hh == 0) __syncthreads();   // #3: half-0 reads done before overwrite
  }

  // GRU epilogue (waves 0-3, 16 rows x 16 cols each) — fast transcendentals,
  // packed pair stores for h_out (f32x2) and A_next h-part (bf16x2).
  if (wave < 4) {
    float br_ = b_i[jcol], bz_ = b_i[1024 + jcol], bn_ = b_i[2048 + jcol];
    float bh = b_hn[jcol];
#pragma unroll
    for (int rr = 0; rr < 4; ++rr) {
      int row = row_base + rr;
      float r = sigm(accs[0][rr] + br_);
      float z = sigm(accs[1][rr] + bz_);
      float n = tanh_fast(accs[2][rr] + bn_ + r * (accs[3][rr] + bh));
      float nh = (1.f - z) * n + z * hv4[rr];
      r_out[((size_t)t * B_DIM + row) * H_DIM + jcol] = nh;
      if (t < T_DIM - 1) {
        int rst = rb[(t + 1) * B_DIM + row];
        float hm = rst ? 0.f : nh;
        float hm_p = __shfl_xor(hm, 1);
        if ((cl & 1) == 0) {
          float2v h2; h2.x = hm; h2.y = hm_p;
          *(float2v*)&h_out[(size_t)row * H_DIM + jcol] = h2;
          unsigned pk = (unsigned)f2bf(hm) | ((unsigned)f2bf(hm_p) << 16);
          *((unsigned*)A_next + (afrag(row, 2048 + jcol, KTC) >> 1)) = pk;
        }
      }
    }
  }
}

// ---------------- fused pred GEMM + e_t / err for step t+1 ----------------
__global__ __launch_bounds__(512, 2) void pred_fused(
    const unsigned short* __restrict__ A_next, const unsigned short* __restrict__ Wp,
    const float* __restrict__ b_p, const float* __restrict__ a_all,
    const unsigned char* __restrict__ rb,
    unsigned short* __restrict__ A_next_w, float* __restrict__ err_out, int t) {
  int lane = threadIdx.x & 63, wave = threadIdx.x >> 6;
  int b = blockIdx.x;
  int ntq = b & 15, mt = b >> 4;

  const short8* A8 = (const short8*)A_next;
  const short8* B8 = (const short8*)Wp;

  const short8* hap = A8 + ((size_t)mt * KTC + 64) * 64 + lane;
  const short8* bp0 = B8 + ((size_t)(ntq * 4 + 0) * KTP) * 64 + lane;
  const short8* bp1 = B8 + ((size_t)(ntq * 4 + 1) * KTP) * 64 + lane;
  const short8* bp2 = B8 + ((size_t)(ntq * 4 + 2) * KTP) * 64 + lane;
  const short8* bp3 = B8 + ((size_t)(ntq * 4 + 3) * KTP) * 64 + lane;

  float4v acc[4];
#pragma unroll
  for (int n = 0; n < 4; ++n) acc[n] = (float4v){0.f, 0.f, 0.f, 0.f};

  {
    int pk0 = wave * 4;   // 8 waves x 4 kt = 32 kt
    short8 Aa[4], B0a[4], B1a[4], B2a[4], B3a[4];
#pragma unroll
    for (int kk = 0; kk < 4; ++kk) Aa[kk] = hap[(size_t)(pk0 + kk) * 64];
#pragma unroll
    for (int kk = 0; kk < 4; ++kk) {
      size_t o = (size_t)(pk0 + kk) * 64;
      B0a[kk] = bp0[o]; B1a[kk] = bp1[o]; B2a[kk] = bp2[o]; B3a[kk] = bp3[o];
    }
#pragma unroll
    for (int kk = 0; kk < 4; ++kk) {
      acc[0] = __builtin_amdgcn_mfma_f32_16x16x32_bf16(Aa[kk], B0a[kk], acc[0], 0, 0, 0);
      acc[1] = __builtin_amdgcn_mfma_f32_16x16x32_bf16(Aa[kk], B1a[kk], acc[1], 0, 0, 0);
      acc[2] = __builtin_amdgcn_mfma_f32_16x16x32_bf16(Aa[kk], B2a[kk], acc[2], 0, 0, 0);
      acc[3] = __builtin_amdgcn_mfma_f32_16x16x32_bf16(Aa[kk], B3a[kk], acc[3], 0, 0, 0);
    }
  }

  __shared__ float4v red[8][4][64];        // 32 KB
  __shared__ float rsum_red[4][4][4];
#pragma unroll
  for (int n = 0; n < 4; ++n) red[wave][n][lane] = acc[n];
  __syncthreads();

  int cl = lane & 15, q = lane >> 4;

  if (wave < 4) {
    float4v s = red[0][wave][lane];
#pragma unroll
    for (int w = 1; w < 8; ++w) s += red[w][wave][lane];

    int coln = (ntq * 4 + wave) * 16 + cl;
    float bp = b_p[coln];
    float rsum[4];
#pragma unroll
    for (int rr = 0; rr < 4; ++rr) {
      int row = mt * 16 + q * 4 + rr;
      float ah = fmaxf(s[rr] + bp, 0.f);
      int rst = rb[(t + 1) * B_DIM + row];
      float am = rst ? 0.f : ah;
      float av = a_all[((size_t)(t + 1) * B_DIM + row) * H_DIM + coln];
      float d = av - am;
      float pos = fmaxf(d, 0.f), neg = fmaxf(-d, 0.f);
      A_next_w[afrag(row, coln, KTC)] = f2bf(pos);
      A_next_w[afrag(row, 1024 + coln, KTC)] = f2bf(neg);
      rsum[rr] = pos + neg;
    }
#pragma unroll
    for (int rr = 0; rr < 4; ++rr) {
      float sv = rsum[rr];
      sv += __shfl_xor(sv, 1);
      sv += __shfl_xor(sv, 2);
      sv += __shfl_xor(sv, 4);
      sv += __shfl_xor(sv, 8);
      if (cl == 0) rsum_red[wave][q][rr] = sv;
    }
  }
  __syncthreads();
  if (wave == 0 && lane < 16) {
    int qq = lane >> 2, rr = lane & 3;
    float sv = rsum_red[0][qq][rr] + rsum_red[1][qq][rr]
             + rsum_red[2][qq][rr] + rsum_red[3][qq][rr];
    int row = mt * 16 + qq * 4 + rr;
    atomicAdd(err_out + (size_t)(t + 1) * B_DIM + row, sv * (1.0f / (float)H_DIM));
  }
}

// ---------------- launch ----------------
extern "C" void kernel_launch(void* const* d_in, const int* in_sizes, int n_in,
                              void* d_out, int out_size, void* d_ws, size_t ws_size,
                              hipStream_t stream) {
  (void)in_sizes; (void)n_in; (void)out_size; (void)ws_size;
  const float* a_all = (const float*)d_in[0];
  const void*  resets = d_in[1];
  const float* W_i  = (const float*)d_in[2];
  const float* b_i  = (const float*)d_in[3];
  const float* W_h  = (const float*)d_in[4];
  const float* b_hn = (const float*)d_in[5];
  const float* W_p  = (const float*)d_in[6];
  const float* b_p  = (const float*)d_in[7];

  float* r_out = (float*)d_out;
  float* err_out = r_out + (size_t)T_DIM * B_DIM * H_DIM;

  char* ws = (char*)d_ws;
  unsigned short* Wg_sw = (unsigned short*)ws; ws += (size_t)256 * 16 * KC * 2;     // 25.2 MB
  unsigned short* Wp_sw = (unsigned short*)ws; ws += (size_t)H_DIM * H_DIM * 2;     // 2 MB
  unsigned short* A0    = (unsigned short*)ws; ws += (size_t)B_DIM * KC * 2;        // 1.5 MB
  unsigned short* A1    = (unsigned short*)ws; ws += (size_t)B_DIM * KC * 2;        // 1.5 MB
  float* h0 = (float*)ws; ws += (size_t)B_DIM * H_DIM * 4;                          // 1 MB
  float* h1 = (float*)ws; ws += (size_t)B_DIM * H_DIM * 4;                          // 1 MB
  unsigned char* rb = (unsigned char*)ws; ws += T_DIM * B_DIM;                      // 32 KB
  int* rflag = (int*)ws; ws += 256;

  hipMemsetAsync(err_out, 0, (size_t)T_DIM * B_DIM * sizeof(float), stream);
  detect_resets<<<1, 256, 0, stream>>>((const int*)resets, rflag);
  decode_resets<<<T_DIM, 256, 0, stream>>>(resets, rflag, rb);
  convert_gates<<<dim3(256, KTC), 256, 0, stream>>>(W_i, W_h, Wg_sw);
  convert_wp<<<dim3(H_DIM / 16, KTP), 256, 0, stream>>>(W_p, Wp_sw);
  init_state<<<B_DIM, 256, 0, stream>>>(a_all, A0, h0, err_out);

  for (int t = 0; t < T_DIM; ++t) {
    const unsigned short* Acur = (t & 1) ? A1 : A0;
    unsigned short* Anext      = (t & 1) ? A0 : A1;
    const float* hcur = (t & 1) ? h1 : h0;
    float* hnext      = (t & 1) ? h0 : h1;
    gates_fused<<<256, 512, 0, stream>>>(
        Acur, Wg_sw, b_i, b_hn, hcur, hnext, Anext, rb, r_out, t);
    if (t < T_DIM - 1)
      pred_fused<<<256, 512, 0, stream>>>(
          Anext, Wp_sw, b_p, a_all, rb, Anext, err_out, t);
  }
}